// Round 4
// baseline (113.539 us; speedup 1.0000x reference)
//
#include <hip/hip_runtime.h>
#include <math.h>

// PartialAttention: LN -> Q/K proj -> scaled QK^T -> rowmax-subtracted exp.
// S=4096, B=2, E=1024, D=64. Out [B,S,S] f32 = 134 MB.
//
// Kernel 1 (ln_proj): 16 rows/block. LN stats (shfl) -> K-chunked dbuf
//   staging of normalized x into LDS -> f32 FMA projection (2x4 tile,
//   coalesced W row reads) -> bias -> f32 LDS tile -> hi/lo RNE split
//   to fragment-ordered q/k in ws (validated round-2 path).
// Kernel 2 (score): per (b, 16-row tile): 16 waves x 16 col-tiles of
//   16x16x32 bf16 MFMA (3-term hi/lo), row-max shfl+LDS, exp, store.
//   Verbatim round-2 (validated, write-roofline).

typedef __attribute__((ext_vector_type(4))) float f32x4;
typedef __attribute__((ext_vector_type(8))) short bf16x8;
typedef __attribute__((ext_vector_type(8))) unsigned short u16x8;

#define SLEN 4096
#define BATCH 2
#define EDIM 1024
#define DDIM 64
#define KCH 256
#define XS_STRIDE 260    // 256 + 4 pad
#define QK_STRIDE 136    // q cols [0,64), k cols [68,132)

__device__ __forceinline__ unsigned short f2bf(float f) {
    unsigned int u = __float_as_uint(f);
    u += 0x7FFFu + ((u >> 16) & 1u);   // RNE to bf16
    return (unsigned short)(u >> 16);
}
__device__ __forceinline__ float bf2f(unsigned short h) {
    return __uint_as_float(((unsigned int)h) << 16);
}

// ---------------- kernel 1: LN + f32 projection + split ----------------
__global__ __launch_bounds__(256, 2) void ln_proj_kernel(
    const float* __restrict__ src, const float* __restrict__ gamma,
    const float* __restrict__ beta,
    const float* __restrict__ Wq, const float* __restrict__ bq,
    const float* __restrict__ Wk, const float* __restrict__ bk,
    unsigned short* __restrict__ qhf, unsigned short* __restrict__ qlf,
    unsigned short* __restrict__ khf, unsigned short* __restrict__ klf)
{
    __shared__ float xs[2][16][XS_STRIDE];   // 33.28 KB (also reused for qk tile)
    __shared__ float2 stats[16];             // mu, rstd
    const int tid  = threadIdx.x;
    const int lane = tid & 63;
    const int wv   = tid >> 6;
    const int bid  = blockIdx.x;           // 0..511
    const int b    = bid >> 8;
    const int s0   = (bid & 255) * 16;

    // ---- phase A: LN stats, 4 rows per wave ----
    for (int ii = 0; ii < 4; ++ii) {
        const int i = wv * 4 + ii;
        const float* row = src + ((size_t)(s0 + i) * BATCH + b) * EDIM;
        float sum = 0.f, sq = 0.f;
#pragma unroll
        for (int k = 0; k < 4; ++k) {
            float4 v = *reinterpret_cast<const float4*>(row + k * 256 + lane * 4);
            sum += v.x + v.y + v.z + v.w;
            sq  += v.x*v.x + v.y*v.y + v.z*v.z + v.w*v.w;
        }
#pragma unroll
        for (int off = 1; off < 64; off <<= 1) {
            sum += __shfl_xor(sum, off);
            sq  += __shfl_xor(sq,  off);
        }
        if (lane == 0) {
            const float mu   = sum * (1.f / EDIM);
            const float rstd = rsqrtf(sq * (1.f / EDIM) - mu * mu + 1e-5f);
            stats[i] = make_float2(mu, rstd);
        }
    }
    __syncthreads();

    // staging roles: thread covers row srow, cols se + t*64 (t=0..3), float4 each
    const int srow = tid >> 4;             // 0..15
    const int se   = (tid & 15) * 4;       // 0..60
    const float* srcrow = src + ((size_t)(s0 + srow) * BATCH + b) * EDIM;
    const float smu = stats[srow].x;
    const float srs = stats[srow].y;

    // compute roles: thread tile = rows {rg*2, rg*2+1} x cols c4..c4+3 (joint 128)
    const int rg = tid >> 5;               // 0..7
    const int c4 = (tid & 31) * 4;         // 0..124
    const bool qside = (c4 < DDIM);
    const float* wbase = qside ? (Wq + c4) : (Wk + (c4 - DDIM));
    float a0[4] = {0.f, 0.f, 0.f, 0.f};
    float a1[4] = {0.f, 0.f, 0.f, 0.f};

    // stage chunk 0
#pragma unroll
    for (int t = 0; t < 4; ++t) {
        const int e = se + t * 64;
        float4 v  = *reinterpret_cast<const float4*>(srcrow + e);
        float4 g  = *reinterpret_cast<const float4*>(gamma + e);
        float4 bt = *reinterpret_cast<const float4*>(beta + e);
        float4 o;
        o.x = (v.x - smu) * srs * g.x + bt.x;
        o.y = (v.y - smu) * srs * g.y + bt.y;
        o.z = (v.z - smu) * srs * g.z + bt.z;
        o.w = (v.w - smu) * srs * g.w + bt.w;
        *reinterpret_cast<float4*>(&xs[0][srow][e]) = o;
    }
    __syncthreads();

    for (int c = 0; c < 4; ++c) {
        const int cur = c & 1;
        if (c < 3) {   // stage next chunk into other buffer
            const int k0 = (c + 1) * KCH;
#pragma unroll
            for (int t = 0; t < 4; ++t) {
                const int e = se + t * 64;
                float4 v  = *reinterpret_cast<const float4*>(srcrow + k0 + e);
                float4 g  = *reinterpret_cast<const float4*>(gamma + k0 + e);
                float4 bt = *reinterpret_cast<const float4*>(beta + k0 + e);
                float4 o;
                o.x = (v.x - smu) * srs * g.x + bt.x;
                o.y = (v.y - smu) * srs * g.y + bt.y;
                o.z = (v.z - smu) * srs * g.z + bt.z;
                o.w = (v.w - smu) * srs * g.w + bt.w;
                *reinterpret_cast<float4*>(&xs[cur ^ 1][srow][e]) = o;
            }
        }
        const float* x0 = &xs[cur][rg * 2 + 0][0];
        const float* x1 = &xs[cur][rg * 2 + 1][0];
        const float* wp = wbase + (size_t)(c * KCH) * DDIM;
#pragma unroll 2
        for (int kk = 0; kk < KCH; kk += 4) {
            float4 w0 = *reinterpret_cast<const float4*>(wp + (size_t)(kk + 0) * DDIM);
            float4 w1 = *reinterpret_cast<const float4*>(wp + (size_t)(kk + 1) * DDIM);
            float4 w2 = *reinterpret_cast<const float4*>(wp + (size_t)(kk + 2) * DDIM);
            float4 w3 = *reinterpret_cast<const float4*>(wp + (size_t)(kk + 3) * DDIM);
            float4 xa = *reinterpret_cast<const float4*>(x0 + kk);
            float4 xb = *reinterpret_cast<const float4*>(x1 + kk);
            a0[0] += xa.x * w0.x; a0[1] += xa.x * w0.y; a0[2] += xa.x * w0.z; a0[3] += xa.x * w0.w;
            a1[0] += xb.x * w0.x; a1[1] += xb.x * w0.y; a1[2] += xb.x * w0.z; a1[3] += xb.x * w0.w;
            a0[0] += xa.y * w1.x; a0[1] += xa.y * w1.y; a0[2] += xa.y * w1.z; a0[3] += xa.y * w1.w;
            a1[0] += xb.y * w1.x; a1[1] += xb.y * w1.y; a1[2] += xb.y * w1.z; a1[3] += xb.y * w1.w;
            a0[0] += xa.z * w2.x; a0[1] += xa.z * w2.y; a0[2] += xa.z * w2.z; a0[3] += xa.z * w2.w;
            a1[0] += xb.z * w2.x; a1[1] += xb.z * w2.y; a1[2] += xb.z * w2.z; a1[3] += xb.z * w2.w;
            a0[0] += xa.w * w3.x; a0[1] += xa.w * w3.y; a0[2] += xa.w * w3.z; a0[3] += xa.w * w3.w;
            a1[0] += xb.w * w3.x; a1[1] += xb.w * w3.y; a1[2] += xb.w * w3.z; a1[3] += xb.w * w3.w;
        }
        __syncthreads();
    }

    // ---- epilogue: bias, write f32 qk tile (reuse xs[0] memory) ----
    float* qk = &xs[0][0][0];
    {
        const float* biasp = qside ? (bq + c4) : (bk + (c4 - DDIM));
        const float4 bv = *reinterpret_cast<const float4*>(biasp);
        const int cb = qside ? c4 : (68 + (c4 - DDIM));
#pragma unroll
        for (int r = 0; r < 2; ++r) {
            float* dst = qk + (rg * 2 + r) * QK_STRIDE + cb;
            const float* a = r ? a1 : a0;
            float4 o;
            o.x = a[0] + bv.x; o.y = a[1] + bv.y;
            o.z = a[2] + bv.z; o.w = a[3] + bv.w;
            *reinterpret_cast<float4*>(dst) = o;
        }
    }
    __syncthreads();

    // ---- phase 3 (verbatim round-2, validated): RNE hi/lo split to frags ----
    // frag elem index: ((b*256 + tile)*2 + dc)*512 + lane*8 + j
    // value = qk[row = l2&15][(isK?68:0) + dc*32 + ((l2>>4)&3)*8 + j] * sc
    {
        const int l2  = tid & 63;
        const int dc  = (tid >> 6) & 1;
        const int isK = tid >> 7;
        const int row = l2 & 15;
        const int d0  = dc * 32 + ((l2 >> 4) & 3) * 8;
        const float* p = &qk[row * QK_STRIDE + (isK ? 68 : 0) + d0];
        const float sc = isK ? 1.0f : 0.125f;   // fold 1/sqrt(D) into q
        u16x8 hvv, lvv;
#pragma unroll
        for (int j = 0; j < 8; ++j) {
            const float vq = p[j] * sc;
            const unsigned short h = f2bf(vq);
            hvv[j] = h;
            lvv[j] = f2bf(vq - bf2f(h));
        }
        const size_t base = ((((size_t)b * 256 + (size_t)(bid & 255)) * 2 + dc) * 512) + (size_t)l2 * 8;
        *reinterpret_cast<u16x8*>((isK ? khf : qhf) + base) = hvv;
        *reinterpret_cast<u16x8*>((isK ? klf : qlf) + base) = lvv;
    }
}

// ---------------- kernel 2: QK^T + rowmax + exp (verbatim round-2) ----------------
__global__ __launch_bounds__(1024, 1) void score_kernel(
    const unsigned short* __restrict__ qhf, const unsigned short* __restrict__ qlf,
    const unsigned short* __restrict__ khf, const unsigned short* __restrict__ klf,
    float* __restrict__ out)
{
    __shared__ float wmax[16 * 16];
    __shared__ float fmax_s[16];
    const int tid = threadIdx.x;
    const int l   = tid & 63;
    const int w   = tid >> 6;        // wave 0..15, owns col-tiles w*16..w*16+15
    const int bid = blockIdx.x;
    const int b   = bid >> 8;
    const int rt  = bid & 255;       // row tile (16 q rows)

    const size_t abase = (((size_t)b * 256 + rt) * 2) * 512 + (size_t)l * 8;
    const bf16x8 qh0 = *reinterpret_cast<const bf16x8*>(qhf + abase);
    const bf16x8 qh1 = *reinterpret_cast<const bf16x8*>(qhf + abase + 512);
    const bf16x8 ql0 = *reinterpret_cast<const bf16x8*>(qlf + abase);
    const bf16x8 ql1 = *reinterpret_cast<const bf16x8*>(qlf + abase + 512);

    f32x4 acc[16];
#pragma unroll
    for (int i = 0; i < 16; ++i) acc[i] = (f32x4){0.f, 0.f, 0.f, 0.f};

#pragma unroll
    for (int i = 0; i < 16; ++i) {
        const int ct = w * 16 + i;
        const size_t kb = (((size_t)b * 256 + ct) * 2) * 512 + (size_t)l * 8;
        const bf16x8 kh0 = *reinterpret_cast<const bf16x8*>(khf + kb);
        const bf16x8 kh1 = *reinterpret_cast<const bf16x8*>(khf + kb + 512);
        const bf16x8 kl0 = *reinterpret_cast<const bf16x8*>(klf + kb);
        const bf16x8 kl1 = *reinterpret_cast<const bf16x8*>(klf + kb + 512);
        f32x4 a = acc[i];
        a = __builtin_amdgcn_mfma_f32_16x16x32_bf16(qh0, kh0, a, 0, 0, 0);
        a = __builtin_amdgcn_mfma_f32_16x16x32_bf16(qh1, kh1, a, 0, 0, 0);
        a = __builtin_amdgcn_mfma_f32_16x16x32_bf16(qh0, kl0, a, 0, 0, 0);
        a = __builtin_amdgcn_mfma_f32_16x16x32_bf16(qh1, kl1, a, 0, 0, 0);
        a = __builtin_amdgcn_mfma_f32_16x16x32_bf16(ql0, kh0, a, 0, 0, 0);
        a = __builtin_amdgcn_mfma_f32_16x16x32_bf16(ql1, kh1, a, 0, 0, 0);
        acc[i] = a;
    }

    // row max: lane holds rows (l>>4)*4+r, col l&15; reduce over cols
    float m4[4];
#pragma unroll
    for (int r = 0; r < 4; ++r) {
        m4[r] = acc[0][r];
#pragma unroll
        for (int i = 1; i < 16; ++i) m4[r] = fmaxf(m4[r], acc[i][r]);
    }
#pragma unroll
    for (int off = 1; off < 16; off <<= 1) {
#pragma unroll
        for (int r = 0; r < 4; ++r) m4[r] = fmaxf(m4[r], __shfl_xor(m4[r], off));
    }
    const int rgrp = l >> 4;
    if ((l & 15) == 0) {
#pragma unroll
        for (int r = 0; r < 4; ++r) wmax[w * 16 + rgrp * 4 + r] = m4[r];
    }
    __syncthreads();
    if (tid < 16) {
        float m = wmax[tid];
#pragma unroll
        for (int ww = 1; ww < 16; ++ww) m = fmaxf(m, wmax[ww * 16 + tid]);
        fmax_s[tid] = m;
    }
    __syncthreads();

    float fm[4];
#pragma unroll
    for (int r = 0; r < 4; ++r) fm[r] = fmax_s[rgrp * 4 + r];
    const int cres = l & 15;
    const size_t obase = ((size_t)b * SLEN + (size_t)rt * 16) * SLEN;
#pragma unroll
    for (int i = 0; i < 16; ++i) {
        const int col = (w * 16 + i) * 16 + cres;
#pragma unroll
        for (int r = 0; r < 4; ++r)
            out[obase + (size_t)(rgrp * 4 + r) * SLEN + col] = __expf(acc[i][r] - fm[r]);
    }
}

extern "C" void kernel_launch(void* const* d_in, const int* in_sizes, int n_in,
                              void* d_out, int out_size, void* d_ws, size_t ws_size,
                              hipStream_t stream) {
    (void)in_sizes; (void)n_in; (void)out_size; (void)ws_size;
    const float* src   = (const float*)d_in[0];
    const float* gamma = (const float*)d_in[1];
    const float* beta  = (const float*)d_in[2];
    const float* Wq    = (const float*)d_in[3];
    const float* bq    = (const float*)d_in[4];
    const float* Wk    = (const float*)d_in[5];
    const float* bk    = (const float*)d_in[6];
    float* out = (float*)d_out;

    // ws: qhf/qlf/khf/klf 1 MB each (2*256*2*512 shorts) = 4 MB total
    unsigned short* ws  = (unsigned short*)d_ws;
    unsigned short* qhf = ws;
    unsigned short* qlf = ws + (1u << 19);
    unsigned short* khf = ws + (2u << 19);
    unsigned short* klf = ws + (3u << 19);

    hipLaunchKernelGGL(ln_proj_kernel, dim3(512), dim3(256), 0, stream,
                       src, gamma, beta, Wq, bq, Wk, bk, qhf, qlf, khf, klf);
    hipLaunchKernelGGL(score_kernel, dim3(512), dim3(1024), 0, stream,
                       qhf, qlf, khf, klf, out);
}

// Round 5
// 75.081 us; speedup vs baseline: 1.5122x; 1.5122x over previous
//
#include <hip/hip_runtime.h>
#include <math.h>

// PartialAttention: LN -> Q/K proj -> scaled QK^T -> rowmax-subtracted exp.
// S=4096, B=2, E=1024, D=64. Out [B,S,S] f32 = 134 MB.
//
// Kernel 0 (wprep): W (unscaled) -> bf16 RNE hi/lo B-fragment arrays.
// Kernel 1 (ln_proj): round-4 skeleton (stats, f32 dbuf staging) with
//   phase 2 swapped to MFMA: A-frags converted in-registers from f32 LDS
//   (proven f2bf split), B-frags from wprep, 4-term hi/lo product.
//   Epilogue -> f32 qk tile -> verbatim proven phase-3 splitter (applies
//   q scale 0.125 there).
// Kernel 2 (score): verbatim round-2/4 (validated, at write roofline).

typedef __attribute__((ext_vector_type(4))) float f32x4;
typedef __attribute__((ext_vector_type(8))) short bf16x8;
typedef __attribute__((ext_vector_type(8))) unsigned short u16x8;

#define SLEN 4096
#define BATCH 2
#define EDIM 1024
#define DDIM 64
#define KCH 256
#define XS_STRIDE 260    // 256 + 4 pad
#define QK_STRIDE 136    // q cols [0,64), k cols [68,132)

__device__ __forceinline__ unsigned short f2bf(float f) {
    unsigned int u = __float_as_uint(f);
    u += 0x7FFFu + ((u >> 16) & 1u);   // RNE to bf16
    return (unsigned short)(u >> 16);
}
__device__ __forceinline__ float bf2f(unsigned short h) {
    return __uint_as_float(((unsigned int)h) << 16);
}

// ---------------- kernel 0: W fragment prep ----------------
// Frag value j at slot (ct, kg, l) = W[kg*32 + ((l>>4)&3)*8 + j][ct*16 + (l&15)]
// slot index = (ct*32 + kg)*64 + l;  ct in 0..7 (joint col tile), kg in 0..31.
// Joint col c < 64 -> Wq, else Wk. No scale (applied in phase 3 of ln_proj).
__global__ __launch_bounds__(256) void wprep_kernel(
    const float* __restrict__ Wq, const float* __restrict__ Wk,
    unsigned short* __restrict__ whf, unsigned short* __restrict__ wlf)
{
    const int slot = blockIdx.x * 256 + threadIdx.x;   // 0..16383
    const int ct = slot >> 11;
    const int kg = (slot >> 6) & 31;
    const int l  = slot & 63;
    const int c  = ct * 16 + (l & 15);
    const int kb = kg * 32 + ((l >> 4) & 3) * 8;
    const float* Wm = (c < DDIM) ? (Wq + c) : (Wk + (c - DDIM));
    u16x8 hv, lv;
#pragma unroll
    for (int j = 0; j < 8; ++j) {
        const float v = Wm[(size_t)(kb + j) * DDIM];
        const unsigned short h = f2bf(v);
        hv[j] = h;
        lv[j] = f2bf(v - bf2f(h));
    }
    *reinterpret_cast<u16x8*>(whf + (size_t)slot * 8) = hv;
    *reinterpret_cast<u16x8*>(wlf + (size_t)slot * 8) = lv;
}

// ---------------- kernel 1: LN + MFMA projection + split ----------------
__global__ __launch_bounds__(256, 2) void ln_proj_kernel(
    const float* __restrict__ src, const float* __restrict__ gamma,
    const float* __restrict__ beta,
    const float* __restrict__ bq, const float* __restrict__ bk,
    const unsigned short* __restrict__ whf, const unsigned short* __restrict__ wlf,
    unsigned short* __restrict__ qhf, unsigned short* __restrict__ qlf,
    unsigned short* __restrict__ khf, unsigned short* __restrict__ klf)
{
    __shared__ float xs[2][16][XS_STRIDE];   // 33.28 KB (reused for qk tile)
    __shared__ float2 stats[16];             // mu, rstd
    const int tid  = threadIdx.x;
    const int lane = tid & 63;
    const int wv   = tid >> 6;
    const int bid  = blockIdx.x;           // 0..511
    const int b    = bid >> 8;
    const int s0   = (bid & 255) * 16;

    // ---- phase A: LN stats, 4 rows per wave (verbatim round-4) ----
    for (int ii = 0; ii < 4; ++ii) {
        const int i = wv * 4 + ii;
        const float* row = src + ((size_t)(s0 + i) * BATCH + b) * EDIM;
        float sum = 0.f, sq = 0.f;
#pragma unroll
        for (int k = 0; k < 4; ++k) {
            float4 v = *reinterpret_cast<const float4*>(row + k * 256 + lane * 4);
            sum += v.x + v.y + v.z + v.w;
            sq  += v.x*v.x + v.y*v.y + v.z*v.z + v.w*v.w;
        }
#pragma unroll
        for (int off = 1; off < 64; off <<= 1) {
            sum += __shfl_xor(sum, off);
            sq  += __shfl_xor(sq,  off);
        }
        if (lane == 0) {
            const float mu   = sum * (1.f / EDIM);
            const float rstd = rsqrtf(sq * (1.f / EDIM) - mu * mu + 1e-5f);
            stats[i] = make_float2(mu, rstd);
        }
    }
    __syncthreads();

    // staging roles (verbatim round-4): row srow, cols se + t*64, float4 each
    const int srow = tid >> 4;             // 0..15
    const int se   = (tid & 15) * 4;       // 0..60
    const float* srcrow = src + ((size_t)(s0 + srow) * BATCH + b) * EDIM;
    const float smu = stats[srow].x;
    const float srs = stats[srow].y;

    // compute roles: wave wv owns joint col-tiles {2wv, 2wv+1}
    const int ct0 = wv * 2;
    const int arow = lane & 15;
    const int koff = (lane >> 4) * 8;      // 0,8,16,24
    f32x4 acc0 = {0.f, 0.f, 0.f, 0.f};
    f32x4 acc1 = {0.f, 0.f, 0.f, 0.f};

    // stage chunk 0 (verbatim round-4)
#pragma unroll
    for (int t = 0; t < 4; ++t) {
        const int e = se + t * 64;
        float4 v  = *reinterpret_cast<const float4*>(srcrow + e);
        float4 g  = *reinterpret_cast<const float4*>(gamma + e);
        float4 bt = *reinterpret_cast<const float4*>(beta + e);
        float4 o;
        o.x = (v.x - smu) * srs * g.x + bt.x;
        o.y = (v.y - smu) * srs * g.y + bt.y;
        o.z = (v.z - smu) * srs * g.z + bt.z;
        o.w = (v.w - smu) * srs * g.w + bt.w;
        *reinterpret_cast<float4*>(&xs[0][srow][e]) = o;
    }
    __syncthreads();

    for (int c = 0; c < 4; ++c) {
        const int cur = c & 1;
        if (c < 3) {   // stage next chunk (verbatim round-4)
            const int k0 = (c + 1) * KCH;
#pragma unroll
            for (int t = 0; t < 4; ++t) {
                const int e = se + t * 64;
                float4 v  = *reinterpret_cast<const float4*>(srcrow + k0 + e);
                float4 g  = *reinterpret_cast<const float4*>(gamma + k0 + e);
                float4 bt = *reinterpret_cast<const float4*>(beta + k0 + e);
                float4 o;
                o.x = (v.x - smu) * srs * g.x + bt.x;
                o.y = (v.y - smu) * srs * g.y + bt.y;
                o.z = (v.z - smu) * srs * g.z + bt.z;
                o.w = (v.w - smu) * srs * g.w + bt.w;
                *reinterpret_cast<float4*>(&xs[cur ^ 1][srow][e]) = o;
            }
        }
        // ---- MFMA compute over this 256-k chunk: 8 x 32-k steps ----
#pragma unroll 2
        for (int ks = 0; ks < 8; ++ks) {
            const int kg = c * 8 + ks;                 // global 32-k step 0..31
            const float* xp = &xs[cur][arow][ks * 32 + koff];
            const float4 v0 = *reinterpret_cast<const float4*>(xp);
            const float4 v1 = *reinterpret_cast<const float4*>(xp + 4);
            const float vv[8] = {v0.x, v0.y, v0.z, v0.w, v1.x, v1.y, v1.z, v1.w};
            bf16x8 ah, al;
#pragma unroll
            for (int j = 0; j < 8; ++j) {
                const unsigned short h = f2bf(vv[j]);
                ah[j] = (short)h;
                al[j] = (short)f2bf(vv[j] - bf2f(h));
            }
            const size_t wb0 = ((size_t)(ct0 * 32 + kg) * 64 + lane) * 8;
            const size_t wb1 = wb0 + (size_t)32 * 64 * 8;   // ct0+1
            const bf16x8 bh0 = *reinterpret_cast<const bf16x8*>(whf + wb0);
            const bf16x8 bl0 = *reinterpret_cast<const bf16x8*>(wlf + wb0);
            const bf16x8 bh1 = *reinterpret_cast<const bf16x8*>(whf + wb1);
            const bf16x8 bl1 = *reinterpret_cast<const bf16x8*>(wlf + wb1);
            acc0 = __builtin_amdgcn_mfma_f32_16x16x32_bf16(ah, bh0, acc0, 0, 0, 0);
            acc0 = __builtin_amdgcn_mfma_f32_16x16x32_bf16(al, bh0, acc0, 0, 0, 0);
            acc0 = __builtin_amdgcn_mfma_f32_16x16x32_bf16(ah, bl0, acc0, 0, 0, 0);
            acc0 = __builtin_amdgcn_mfma_f32_16x16x32_bf16(al, bl0, acc0, 0, 0, 0);
            acc1 = __builtin_amdgcn_mfma_f32_16x16x32_bf16(ah, bh1, acc1, 0, 0, 0);
            acc1 = __builtin_amdgcn_mfma_f32_16x16x32_bf16(al, bh1, acc1, 0, 0, 0);
            acc1 = __builtin_amdgcn_mfma_f32_16x16x32_bf16(ah, bl1, acc1, 0, 0, 0);
            acc1 = __builtin_amdgcn_mfma_f32_16x16x32_bf16(al, bl1, acc1, 0, 0, 0);
        }
        __syncthreads();
    }

    // ---- epilogue: bias, write f32 qk tile (reuse xs[0]); C layout:
    // col = lane&15 (within tile), row = (lane>>4)*4 + r  [validated] ----
    float* qk = &xs[0][0][0];
    {
        const int cj0 = ct0 * 16 + (lane & 15);
        const int cj1 = cj0 + 16;
        const int r0  = (lane >> 4) * 4;
        const float bv0 = (cj0 < DDIM) ? bq[cj0] : bk[cj0 - DDIM];
        const float bv1 = (cj1 < DDIM) ? bq[cj1] : bk[cj1 - DDIM];
        const int cb0 = (cj0 < DDIM) ? cj0 : (68 + cj0 - DDIM);
        const int cb1 = (cj1 < DDIM) ? cj1 : (68 + cj1 - DDIM);
#pragma unroll
        for (int r = 0; r < 4; ++r) {
            qk[(r0 + r) * QK_STRIDE + cb0] = acc0[r] + bv0;
            qk[(r0 + r) * QK_STRIDE + cb1] = acc1[r] + bv1;
        }
    }
    __syncthreads();

    // ---- phase 3 (verbatim round-2/4, validated): RNE hi/lo split ----
    // frag elem index: ((b*256 + tile)*2 + dc)*512 + lane*8 + j
    // value = qk[row = l2&15][(isK?68:0) + dc*32 + ((l2>>4)&3)*8 + j] * sc
    {
        const int l2  = tid & 63;
        const int dc  = (tid >> 6) & 1;
        const int isK = tid >> 7;
        const int row = l2 & 15;
        const int d0  = dc * 32 + ((l2 >> 4) & 3) * 8;
        const float* p = &qk[row * QK_STRIDE + (isK ? 68 : 0) + d0];
        const float sc = isK ? 1.0f : 0.125f;   // fold 1/sqrt(D) into q
        u16x8 hvv, lvv;
#pragma unroll
        for (int j = 0; j < 8; ++j) {
            const float vq = p[j] * sc;
            const unsigned short h = f2bf(vq);
            hvv[j] = h;
            lvv[j] = f2bf(vq - bf2f(h));
        }
        const size_t base = ((((size_t)b * 256 + (size_t)(bid & 255)) * 2 + dc) * 512) + (size_t)l2 * 8;
        *reinterpret_cast<u16x8*>((isK ? khf : qhf) + base) = hvv;
        *reinterpret_cast<u16x8*>((isK ? klf : qlf) + base) = lvv;
    }
}

// ---------------- kernel 2: QK^T + rowmax + exp (verbatim round-2/4) ----------------
__global__ __launch_bounds__(1024, 1) void score_kernel(
    const unsigned short* __restrict__ qhf, const unsigned short* __restrict__ qlf,
    const unsigned short* __restrict__ khf, const unsigned short* __restrict__ klf,
    float* __restrict__ out)
{
    __shared__ float wmax[16 * 16];
    __shared__ float fmax_s[16];
    const int tid = threadIdx.x;
    const int l   = tid & 63;
    const int w   = tid >> 6;        // wave 0..15, owns col-tiles w*16..w*16+15
    const int bid = blockIdx.x;
    const int b   = bid >> 8;
    const int rt  = bid & 255;       // row tile (16 q rows)

    const size_t abase = (((size_t)b * 256 + rt) * 2) * 512 + (size_t)l * 8;
    const bf16x8 qh0 = *reinterpret_cast<const bf16x8*>(qhf + abase);
    const bf16x8 qh1 = *reinterpret_cast<const bf16x8*>(qhf + abase + 512);
    const bf16x8 ql0 = *reinterpret_cast<const bf16x8*>(qlf + abase);
    const bf16x8 ql1 = *reinterpret_cast<const bf16x8*>(qlf + abase + 512);

    f32x4 acc[16];
#pragma unroll
    for (int i = 0; i < 16; ++i) acc[i] = (f32x4){0.f, 0.f, 0.f, 0.f};

#pragma unroll
    for (int i = 0; i < 16; ++i) {
        const int ct = w * 16 + i;
        const size_t kb = (((size_t)b * 256 + ct) * 2) * 512 + (size_t)l * 8;
        const bf16x8 kh0 = *reinterpret_cast<const bf16x8*>(khf + kb);
        const bf16x8 kh1 = *reinterpret_cast<const bf16x8*>(khf + kb + 512);
        const bf16x8 kl0 = *reinterpret_cast<const bf16x8*>(klf + kb);
        const bf16x8 kl1 = *reinterpret_cast<const bf16x8*>(klf + kb + 512);
        f32x4 a = acc[i];
        a = __builtin_amdgcn_mfma_f32_16x16x32_bf16(qh0, kh0, a, 0, 0, 0);
        a = __builtin_amdgcn_mfma_f32_16x16x32_bf16(qh1, kh1, a, 0, 0, 0);
        a = __builtin_amdgcn_mfma_f32_16x16x32_bf16(qh0, kl0, a, 0, 0, 0);
        a = __builtin_amdgcn_mfma_f32_16x16x32_bf16(qh1, kl1, a, 0, 0, 0);
        a = __builtin_amdgcn_mfma_f32_16x16x32_bf16(ql0, kh0, a, 0, 0, 0);
        a = __builtin_amdgcn_mfma_f32_16x16x32_bf16(ql1, kh1, a, 0, 0, 0);
        acc[i] = a;
    }

    // row max: lane holds rows (l>>4)*4+r, col l&15; reduce over cols
    float m4[4];
#pragma unroll
    for (int r = 0; r < 4; ++r) {
        m4[r] = acc[0][r];
#pragma unroll
        for (int i = 1; i < 16; ++i) m4[r] = fmaxf(m4[r], acc[i][r]);
    }
#pragma unroll
    for (int off = 1; off < 16; off <<= 1) {
#pragma unroll
        for (int r = 0; r < 4; ++r) m4[r] = fmaxf(m4[r], __shfl_xor(m4[r], off));
    }
    const int rgrp = l >> 4;
    if ((l & 15) == 0) {
#pragma unroll
        for (int r = 0; r < 4; ++r) wmax[w * 16 + rgrp * 4 + r] = m4[r];
    }
    __syncthreads();
    if (tid < 16) {
        float m = wmax[tid];
#pragma unroll
        for (int ww = 1; ww < 16; ++ww) m = fmaxf(m, wmax[ww * 16 + tid]);
        fmax_s[tid] = m;
    }
    __syncthreads();

    float fm[4];
#pragma unroll
    for (int r = 0; r < 4; ++r) fm[r] = fmax_s[rgrp * 4 + r];
    const int cres = l & 15;
    const size_t obase = ((size_t)b * SLEN + (size_t)rt * 16) * SLEN;
#pragma unroll
    for (int i = 0; i < 16; ++i) {
        const int col = (w * 16 + i) * 16 + cres;
#pragma unroll
        for (int r = 0; r < 4; ++r)
            out[obase + (size_t)(rgrp * 4 + r) * SLEN + col] = __expf(acc[i][r] - fm[r]);
    }
}

extern "C" void kernel_launch(void* const* d_in, const int* in_sizes, int n_in,
                              void* d_out, int out_size, void* d_ws, size_t ws_size,
                              hipStream_t stream) {
    (void)in_sizes; (void)n_in;
    const float* src   = (const float*)d_in[0];
    const float* gamma = (const float*)d_in[1];
    const float* beta  = (const float*)d_in[2];
    const float* Wq    = (const float*)d_in[3];
    const float* bq    = (const float*)d_in[4];
    const float* Wk    = (const float*)d_in[5];
    const float* bk    = (const float*)d_in[6];
    float* out = (float*)d_out;

    // ws: qhf/qlf/khf/klf 1 MB each; then whf/wlf 256 KB each.
    unsigned short* ws  = (unsigned short*)d_ws;
    unsigned short* qhf = ws;
    unsigned short* qlf = ws + (1u << 19);
    unsigned short* khf = ws + (2u << 19);
    unsigned short* klf = ws + (3u << 19);

    const size_t wfrag_shorts = 131072;             // 256 KB each
    const size_t need_bytes = (4u << 20) + 2 * 256 * 1024;
    unsigned short *whf, *wlf;
    if (ws_size >= need_bytes) {
        whf = ws + (4u << 19);
        wlf = whf + wfrag_shorts;
    } else {
        // park W frags in the tail of d_out: wprep writes -> ln_proj reads ->
        // score overwrites every byte of d_out afterwards (stream-ordered).
        const size_t out_bytes = (size_t)out_size * 4;
        char* tail = (char*)d_out + (out_bytes - (2 * 256 * 1024 + 4096));
        whf = (unsigned short*)tail;
        wlf = whf + wfrag_shorts;
    }

    hipLaunchKernelGGL(wprep_kernel, dim3(64), dim3(256), 0, stream,
                       Wq, Wk, whf, wlf);
    hipLaunchKernelGGL(ln_proj_kernel, dim3(512), dim3(256), 0, stream,
                       src, gamma, beta, bq, bk, whf, wlf, qhf, qlf, khf, klf);
    hipLaunchKernelGGL(score_kernel, dim3(512), dim3(1024), 0, stream,
                       qhf, qlf, khf, klf, out);
}